// Round 3
// baseline (748.623 us; speedup 1.0000x reference)
//
#include <hip/hip_runtime.h>
#include <hip/hip_bf16.h>
#include <stdint.h>

using bf16 = __hip_bfloat16;
typedef __attribute__((ext_vector_type(8))) short bf16x8;
typedef __attribute__((ext_vector_type(4))) float f32x4;

union U8 { uint4 u; bf16x8 h; };

static __device__ __forceinline__ float b2f(bf16 v) { return __bfloat162float(v); }
static __device__ __forceinline__ bf16  f2b(float v) { return __float2bfloat16(v); }
static __device__ __forceinline__ float toF(float v) { return v; }
static __device__ __forceinline__ float toF(bf16 v)  { return __bfloat162float(v); }
static __device__ __forceinline__ void stF(float* p, float v) { *p = v; }
static __device__ __forceinline__ void stF(bf16* p,  float v) { *p = f2b(v); }
static __device__ __forceinline__ float bfu(unsigned short x) {
  union { unsigned int i; float f; } z; z.i = ((unsigned int)x) << 16; return z.f;
}

// direct global -> LDS async copy, 16B per lane; lds dest = wave-uniform base + lane*16
static __device__ __forceinline__ void gload16(const bf16* g, const short* l) {
  __builtin_amdgcn_global_load_lds(
      (const __attribute__((address_space(1))) void*)g,
      (__attribute__((address_space(3))) void*)l, 16, 0, 0);
}

// ---------------- weight convert: w[k][n] fp32 -> wt[n][k] bf16, k zero-padded to Kp ----
__global__ __launch_bounds__(256) void convert_wt_kernel(
    const float* __restrict__ w, bf16* __restrict__ wt, int K, int N, int Kp)
{
  int idx = blockIdx.x * 256 + threadIdx.x;
  if (idx >= N * Kp) return;
  int n = idx / Kp, k = idx % Kp;
  float v = (k < K) ? w[(size_t)k * N + n] : 0.f;
  wt[idx] = f2b(v);
}

// ---------------- bias concat: [q_b | k_b | v_b] -> 1080 floats ------------------------
__global__ __launch_bounds__(256) void concat_bias_kernel(
    const float* __restrict__ qb, const float* __restrict__ kb,
    const float* __restrict__ vb, float* __restrict__ o)
{
  int i = blockIdx.x * 256 + threadIdx.x;
  if (i >= 1080) return;
  o[i] = (i < 180) ? qb[i] : (i < 360) ? kb[i - 180] : vb[i - 360];
}

// ---------------- bias precompute: bias_f[hh][r][kk] = rpb[rpi[r,kk]*6+hh] --------------
__global__ __launch_bounds__(256) void bias_pre_kernel(
    const int* __restrict__ rpi, const float* __restrict__ rpb, float* __restrict__ bias_f)
{
  int e = blockIdx.x * 256 + threadIdx.x;
  if (e >= 6 * 64 * 144) return;
  int hh = e / 9216, rk = e % 9216;
  bias_f[e] = rpb[rpi[rk] * 6 + hh];
}

// ---------------- LN1 + DWT: x fp32 (2,256,256,180) -> xd bf16 (2,128,128,720) ----------
__global__ __launch_bounds__(256) void ln_dwt_kernel(
    const float* __restrict__ x, const float* __restrict__ w, const float* __restrict__ bia,
    bf16* __restrict__ xd)
{
  __shared__ float nrm[4][180];
  int blk = blockIdx.x;
  int j = blk & 127; int i = (blk >> 7) & 127; int b = blk >> 14;
  int wave = threadIdx.x >> 6, lane = threadIdx.x & 63;
  int ty = wave >> 1, tx = wave & 1;
  size_t tok = (size_t)b * 65536 + (size_t)(2 * i + ty) * 256 + (size_t)(2 * j + tx);
  const float* xp = x + tok * 180;
  float v0 = xp[lane];
  float v1 = xp[lane + 64];
  float v2 = (lane < 52) ? xp[lane + 128] : 0.f;
  float s = v0 + v1 + v2, ss = v0 * v0 + v1 * v1 + v2 * v2;
  #pragma unroll
  for (int m = 32; m; m >>= 1) { s += __shfl_xor(s, m); ss += __shfl_xor(ss, m); }
  float mu = s * (1.f / 180.f);
  float rstd = rsqrtf(ss * (1.f / 180.f) - mu * mu + 1e-5f);
  nrm[wave][lane]      = (v0 - mu) * rstd * w[lane]      + bia[lane];
  nrm[wave][lane + 64] = (v1 - mu) * rstd * w[lane + 64] + bia[lane + 64];
  if (lane < 52)
    nrm[wave][lane + 128] = (v2 - mu) * rstd * w[lane + 128] + bia[lane + 128];
  __syncthreads();
  bf16* op = xd + (size_t)blk * 720;
  for (int o = threadIdx.x; o < 720; o += 256) {
    int g = o / 180, c = o % 180;
    float a = nrm[0][c], bb = nrm[1][c], cc = nrm[2][c], dd = nrm[3][c];
    float r = (g == 0) ? (a + bb + cc + dd)
            : (g == 1) ? (-a - bb + cc + dd)
            : (g == 2) ? (-a + bb - cc + dd)
                       : (a - bb - cc + dd);
    op[o] = f2b(r * 0.5f);
  }
}

// ---------------- plain LN: x1 bf16 (131072,180) -> y bf16 stride 192 (zero-padded) -----
__global__ __launch_bounds__(256) void ln_kernel(
    const bf16* __restrict__ x, const float* __restrict__ w, const float* __restrict__ bia,
    bf16* __restrict__ y)
{
  int wave = threadIdx.x >> 6, lane = threadIdx.x & 63;
  size_t tok = (size_t)blockIdx.x * 4 + wave;
  const bf16* xp = x + tok * 180;
  float v0 = b2f(xp[lane]);
  float v1 = b2f(xp[lane + 64]);
  float v2 = (lane < 52) ? b2f(xp[lane + 128]) : 0.f;
  float s = v0 + v1 + v2, ss = v0 * v0 + v1 * v1 + v2 * v2;
  #pragma unroll
  for (int m = 32; m; m >>= 1) { s += __shfl_xor(s, m); ss += __shfl_xor(ss, m); }
  float mu = s * (1.f / 180.f);
  float rstd = rsqrtf(ss * (1.f / 180.f) - mu * mu + 1e-5f);
  bf16* yp = y + tok * 192;
  yp[lane]      = f2b((v0 - mu) * rstd * w[lane]      + bia[lane]);
  yp[lane + 64] = f2b((v1 - mu) * rstd * w[lane + 64] + bia[lane + 64]);
  if (lane < 52)
    yp[lane + 128] = f2b((v2 - mu) * rstd * w[lane + 128] + bia[lane + 128]);
  else
    yp[lane + 128] = f2b(0.f);
}

// ---------------- MFMA GEMM: out = ep(A@Wt^T + bias [, res]) ----------------------------
// Block tile 128 x 192, waves 2x2 (per-wave 64x96, acc[4][6]).
// Staging via global_load_lds (direct HBM->LDS, 16B/lane). K-tail: A row slop-reads are
// multiplied by Wt's zero-padded k in [K, Kp) -> contribute 0. OOB B rows clamped; their
// acc cols are never stored.
template <int EP, typename TRes, typename TOut>
__global__ __launch_bounds__(256) void gemm_mfma(
    const bf16* __restrict__ A, const bf16* __restrict__ Wt,
    const float* __restrict__ bias, const TRes* __restrict__ res,
    TOut* __restrict__ out, int N, int lda, int Kp, int ldout, int ldres)
{
  __shared__ __align__(16) short Al[128 * 32];
  __shared__ __align__(16) short Bl[192 * 32];
  int tid = threadIdx.x;
  int wave = tid >> 6, lane = tid & 63;
  int wy = wave >> 1, wx = wave & 1;
  int m0 = blockIdx.x * 128, n0 = blockIdx.y * 192;

  f32x4 acc[4][6] = {};

  int ar0 = tid >> 2;                 // 0..63
  int ac  = (tid & 3) * 8;            // 0,8,16,24
  const bf16* gA0 = A + (size_t)(m0 + ar0) * lda + ac;
  const bf16* gA1 = A + (size_t)(m0 + 64 + ar0) * lda + ac;
  int br0 = n0 + ar0, br1 = n0 + ar0 + 64, br2 = n0 + ar0 + 128;
  br0 = (br0 < N) ? br0 : (N - 1);
  br1 = (br1 < N) ? br1 : (N - 1);
  br2 = (br2 < N) ? br2 : (N - 1);
  const bf16* gB0 = Wt + (size_t)br0 * Kp + ac;
  const bf16* gB1 = Wt + (size_t)br1 * Kp + ac;
  const bf16* gB2 = Wt + (size_t)br2 * Kp + ac;

  int wb = wave * 512;                // wave-uniform LDS base (shorts)
  int fm = lane & 15, quad = lane >> 4;
  const short* afp = &Al[(wy * 64 + fm) * 32 + quad * 8];
  const short* bfp = &Bl[(wx * 96 + fm) * 32 + quad * 8];

  for (int k0 = 0; k0 < Kp; k0 += 32) {
    __syncthreads();
    gload16(gA0 + k0, &Al[wb]);
    gload16(gA1 + k0, &Al[2048 + wb]);
    gload16(gB0 + k0, &Bl[wb]);
    gload16(gB1 + k0, &Bl[2048 + wb]);
    gload16(gB2 + k0, &Bl[4096 + wb]);
    __syncthreads();

    bf16x8 af0 = *(const bf16x8*)(afp);
    bf16x8 af1 = *(const bf16x8*)(afp + 16 * 32);
    bf16x8 af2 = *(const bf16x8*)(afp + 32 * 32);
    bf16x8 af3 = *(const bf16x8*)(afp + 48 * 32);
    #pragma unroll
    for (int nt = 0; nt < 6; nt++) {
      bf16x8 bfr = *(const bf16x8*)(bfp + nt * 16 * 32);
      acc[0][nt] = __builtin_amdgcn_mfma_f32_16x16x32_bf16(af0, bfr, acc[0][nt], 0, 0, 0);
      acc[1][nt] = __builtin_amdgcn_mfma_f32_16x16x32_bf16(af1, bfr, acc[1][nt], 0, 0, 0);
      acc[2][nt] = __builtin_amdgcn_mfma_f32_16x16x32_bf16(af2, bfr, acc[2][nt], 0, 0, 0);
      acc[3][nt] = __builtin_amdgcn_mfma_f32_16x16x32_bf16(af3, bfr, acc[3][nt], 0, 0, 0);
    }
  }

  #pragma unroll
  for (int nt = 0; nt < 6; nt++) {
    int col = n0 + wx * 96 + nt * 16 + fm;
    if (col >= N) continue;
    float bv = bias[col];
    #pragma unroll
    for (int mt = 0; mt < 4; mt++) {
      int row0 = m0 + wy * 64 + mt * 16 + quad * 4;
      #pragma unroll
      for (int r = 0; r < 4; r++) {
        int row = row0 + r;
        float v = acc[mt][nt][r] + bv;
        if constexpr (EP == 1) v += toF(res[(size_t)row * ldres + col]);
        if constexpr (EP == 2) v = 0.5f * v * (1.f + erff(v * 0.70710678118654752f));
        stF(&out[(size_t)row * ldout + col], v);
      }
    }
  }
}

// ---------------- MFMA attention: one block per (window, head) --------------------------
// qkv: bf16 fused (32768 x 1080): q cols 0..179, k 180..359, v 360..1079.
// xw out bf16 stride 720; bias_f: [6][64][144]
__global__ __launch_bounds__(256) void attn_kernel(
    const bf16* __restrict__ qkv, const float* __restrict__ bias_f, bf16* __restrict__ xw)
{
  __shared__ short tokl[160];                       // 144 used; -1 = OOB
  __shared__ __align__(16) short Pl[64 * 168];      // P (bf16 bits), cols 144..159 zeroed
  __shared__ __align__(16) short Vt[128 * 168];     // V^T [dd][kk^swz], rows 120..127 zero
  const float scale = 0.18257418583505536f;  // 30^-0.5
  int blk = blockIdx.x;
  int hh = blk % 6; int wid = blk / 6;
  int wj = wid & 15; int wi = (wid >> 4) & 15; int b = wid >> 8;
  int tid = threadIdx.x;
  int wave = tid >> 6, lane = tid & 63;
  int fm = lane & 15, quad = lane >> 4;
  const unsigned int* qkvu = (const unsigned int*)qkv;   // row stride 540 uints
  int hh15 = hh * 15, hh60 = hh * 60;

  // ---- phase 0: kv-position token table ----
  if (tid < 144) {
    int ky = tid / 12, kx = tid % 12;
    int gy = wi * 8 - 4 + ky, gx = wj * 8 - 4 + kx;
    tokl[tid] = (gy >= 0 && gy < 128 && gx >= 0 && gx < 128)
              ? (short)(b * 16384 + gy * 128 + gx) : (short)-1;
  }
  __syncthreads();

  // ---- phase 1: V staging (vectorized). v row offset = 180 uints ----
  {
    int kg = tid & 15, oct = tid >> 4;              // kk offset / dd-oct
    int colx = (oct & 1) << 4;                      // swizzle: col ^= (dd&8)<<1
    #pragma unroll
    for (int p = 0; p < 10; p++) {
      int kk = p * 16 + kg;
      int t = (kk < 144) ? (int)tokl[kk] : -1;
      U8 vv; vv.u = make_uint4(0, 0, 0, 0);
      if (oct < 15 && t >= 0)
        vv.u = *(const uint4*)(qkvu + (size_t)t * 540 + 180 + hh60 + oct * 4);
      short* wp = &Vt[oct * 8 * 168 + (kk ^ colx)];
      #pragma unroll
      for (int jj = 0; jj < 8; jj++) wp[jj * 168] = vv.h[jj];
    }
  }

  // ---- phase 2: QK MFMA with direct-from-global fragments ----
  f32x4 sacc[9] = {};
  {
    U8 qf;
    int r = wave * 16 + fm;
    int gy = wi * 8 + (r >> 3), gx = wj * 8 + (r & 7);
    const unsigned int* qp = qkvu + (size_t)(b * 16384 + gy * 128 + gx) * 540 + hh15 + quad * 4;
    qf.u.x = qp[0]; qf.u.y = qp[1]; qf.u.z = qp[2]; qf.u.w = qp[3];
    if (quad == 3) qf.u.w = 0;                      // zero pad channels 30,31
    #pragma unroll
    for (int nt = 0; nt < 9; nt++) {
      int t = (int)tokl[nt * 16 + fm];
      U8 kf; kf.u = make_uint4(0, 0, 0, 0);
      if (t >= 0) {
        const unsigned int* kp = qkvu + (size_t)t * 540 + 90 + hh15 + quad * 4;
        kf.u.x = kp[0]; kf.u.y = kp[1]; kf.u.z = kp[2]; kf.u.w = kp[3];
      }
      if (quad == 3) kf.u.w = 0;
      sacc[nt] = __builtin_amdgcn_mfma_f32_16x16x32_bf16(qf.h, kf.h, sacc[nt], 0, 0, 0);
    }
  }

  // ---- phase 3: softmax in registers ----
  float sv[9][4];
  const float* bias_g = bias_f + hh * 9216;
  {
    #pragma unroll
    for (int r = 0; r < 4; r++) {
      int row = wave * 16 + quad * 4 + r;
      #pragma unroll
      for (int nt = 0; nt < 9; nt++)
        sv[nt][r] = sacc[nt][r] * scale + bias_g[row * 144 + nt * 16 + fm];
    }
    float mr[4], sr[4];
    #pragma unroll
    for (int r = 0; r < 4; r++) {
      float m = sv[0][r];
      #pragma unroll
      for (int nt = 1; nt < 9; nt++) m = fmaxf(m, sv[nt][r]);
      #pragma unroll
      for (int sh = 1; sh < 16; sh <<= 1) m = fmaxf(m, __shfl_xor(m, sh));
      mr[r] = m;
    }
    #pragma unroll
    for (int r = 0; r < 4; r++) {
      float s = 0.f;
      #pragma unroll
      for (int nt = 0; nt < 9; nt++) { sv[nt][r] = __expf(sv[nt][r] - mr[r]); s += sv[nt][r]; }
      #pragma unroll
      for (int sh = 1; sh < 16; sh <<= 1) s += __shfl_xor(s, sh);
      sr[r] = 1.f / s;
    }
    #pragma unroll
    for (int r = 0; r < 4; r++)
      #pragma unroll
      for (int nt = 0; nt < 9; nt++) sv[nt][r] *= sr[r];
  }

  // ---- phase 4: write normalized P; zero pad cols 144..159 ----
  #pragma unroll
  for (int r = 0; r < 4; r++) {
    int row = wave * 16 + quad * 4 + r;
    #pragma unroll
    for (int nt = 0; nt < 9; nt++)
      Pl[row * 168 + nt * 16 + fm] = (short)__bfloat16_as_ushort(f2b(sv[nt][r]));
  }
  #pragma unroll
  for (int j2 = 0; j2 < 2; j2++) {
    int idx = lane * 2 + j2;
    int row = wave * 16 + (idx >> 3);
    *(unsigned int*)&Pl[row * 168 + 144 + (idx & 7) * 2] = 0u;
  }
  __syncthreads();   // V staging complete (P rows are wave-local)

  // ---- phase 5: O = P @ Vt^T  (M=64, N=128, K=160) ----
  int sread = (fm & 8) << 1;
  bf16x8 pf[5];
  const short* prow = &Pl[(wave * 16 + fm) * 168];
  #pragma unroll
  for (int ks = 0; ks < 5; ks++) pf[ks] = *(const bf16x8*)&prow[ks * 32 + quad * 8];
  f32x4 oacc[8] = {};
  #pragma unroll
  for (int ks = 0; ks < 5; ks++) {
    #pragma unroll
    for (int nt = 0; nt < 8; nt++) {
      bf16x8 vf = *(const bf16x8*)&Vt[(nt * 16 + fm) * 168 + ((ks * 32 + quad * 8) ^ sread)];
      oacc[nt] = __builtin_amdgcn_mfma_f32_16x16x32_bf16(pf[ks], vf, oacc[nt], 0, 0, 0);
    }
  }
  #pragma unroll
  for (int nt = 0; nt < 8; nt++) {
    int col = nt * 16 + fm;
    if (col >= 120) continue;
    #pragma unroll
    for (int r = 0; r < 4; r++) {
      int row = wave * 16 + quad * 4 + r;
      int gy = wi * 8 + (row >> 3), gx = wj * 8 + (row & 7);
      xw[((size_t)b * 16384 + (size_t)gy * 128 + gx) * 720 + hh * 120 + col] = f2b(oacc[nt][r]);
    }
  }
}

// ---------------- IDWT: xw bf16 (.,720) -> xr bf16 stride 192 (zero-padded 180..191) ----
__global__ __launch_bounds__(256) void idwt_kernel(
    const bf16* __restrict__ xw, bf16* __restrict__ xr)
{
  int gid = blockIdx.x * 256 + threadIdx.x;
  int cu = gid % 24;
  int tokn = gid / 24;
  int c = cu * 8;
  bf16* op = xr + (size_t)tokn * 192 + c;
  uint4 outv = make_uint4(0, 0, 0, 0);
  if (c < 184) {
    int x2 = tokn & 255, y2 = (tokn >> 8) & 255, bb = tokn >> 16;
    int ii = y2 >> 1, jj = x2 >> 1, py = y2 & 1, px = x2 & 1;
    const unsigned short* p = (const unsigned short*)xw
        + ((size_t)bb * 16384 + (size_t)ii * 128 + jj) * 720 + c;
    union QW { uint4 v; uint2 u[2]; unsigned short s[8]; } a_, b_, c_, d_, o_;
    a_.u[0] = *(const uint2*)(p);        a_.u[1] = *(const uint2*)(p + 4);
    b_.u[0] = *(const uint2*)(p + 180);  b_.u[1] = *(const uint2*)(p + 184);
    c_.u[0] = *(const uint2*)(p + 360);  c_.u[1] = *(const uint2*)(p + 364);
    d_.u[0] = *(const uint2*)(p + 540);  d_.u[1] = *(const uint2*)(p + 544);
    #pragma unroll
    for (int t = 0; t < 8; t++) {
      float ll = bfu(a_.s[t]), lh = bfu(b_.s[t]), hl = bfu(c_.s[t]), hv = bfu(d_.s[t]);
      float r;
      if (py == 0) r = (px == 0) ? (ll - lh - hl + hv) : (ll - lh + hl - hv);
      else         r = (px == 0) ? (ll + lh - hl - hv) : (ll + lh + hl + hv);
      o_.s[t] = (c + t < 180) ? __bfloat16_as_ushort(f2b(r * 0.5f)) : (unsigned short)0;
    }
    outv = o_.v;
  }
  *(uint4*)op = outv;
}

extern "C" void kernel_launch(void* const* d_in, const int* in_sizes, int n_in,
                              void* d_out, int out_size, void* d_ws, size_t ws_size,
                              hipStream_t stream) {
  (void)in_sizes; (void)n_in; (void)out_size; (void)ws_size;
  const float* x      = (const float*)d_in[0];
  const int*   rpi    = (const int*)  d_in[2];
  const float* n1w    = (const float*)d_in[5];
  const float* n1b    = (const float*)d_in[6];
  const float* q_w    = (const float*)d_in[9];
  const float* q_b    = (const float*)d_in[10];
  const float* k_w    = (const float*)d_in[11];
  const float* k_b    = (const float*)d_in[12];
  const float* v_w    = (const float*)d_in[13];
  const float* v_b    = (const float*)d_in[14];
  const float* rpb    = (const float*)d_in[15];
  const float* proj_w = (const float*)d_in[16];
  const float* proj_b = (const float*)d_in[17];
  const float* n2w    = (const float*)d_in[18];
  const float* n2b    = (const float*)d_in[19];
  const float* fc1_w  = (const float*)d_in[20];
  const float* fc1_b  = (const float*)d_in[21];
  const float* fc2_w  = (const float*)d_in[22];
  const float* fc2_b  = (const float*)d_in[23];
  float* out = (float*)d_out;

  // ---- workspace layout (bf16 elements) ----
  bf16* xd  = (bf16*)d_ws;                  // 32768 x 720   (reused: xw, then yb)
  bf16* qkv = xd + 23592960;                // 32768 x 1080  (q|k|v fused)
  bf16* x1  = qkv + 35389440;               // 131072 x 180
  bf16* hb  = x1 + 23592960;                // 131072 x 360
  bf16* wts = hb + 47185920;
  bf16* qkvwt = wts;                        // 1080 x 736 (q rows 0..179, k 180..359, v 360..1079)
  bf16* pwt  = qkvwt + 794880;              // 180 x 192
  bf16* f1wt = pwt + 34560;                 // 360 x 192
  bf16* f2wt = f1wt + 69120;                // 180 x 384
  float* bias_f = (float*)(f2wt + 69120);   // 6 x 64 x 144 fp32
  float* qkv_b  = bias_f + 55296;           // 1080 fp32
  bf16* xw = xd;
  bf16* xr = qkv + 10223616;                // 131072 x 192 (tail of qkv region)
  bf16* yb = xd;

  convert_wt_kernel<<<518,  256, 0, stream>>>(q_w,    qkvwt,          720, 180, 736);
  convert_wt_kernel<<<518,  256, 0, stream>>>(k_w,    qkvwt + 132480, 720, 180, 736);
  convert_wt_kernel<<<2071, 256, 0, stream>>>(v_w,    qkvwt + 264960, 720, 720, 736);
  convert_wt_kernel<<<135,  256, 0, stream>>>(proj_w, pwt,  180, 180, 192);
  convert_wt_kernel<<<270,  256, 0, stream>>>(fc1_w,  f1wt, 180, 360, 192);
  convert_wt_kernel<<<270,  256, 0, stream>>>(fc2_w,  f2wt, 360, 180, 384);
  concat_bias_kernel<<<5, 256, 0, stream>>>(q_b, k_b, v_b, qkv_b);
  bias_pre_kernel<<<216, 256, 0, stream>>>(rpi, rpb, bias_f);

  ln_dwt_kernel<<<32768, 256, 0, stream>>>(x, n1w, n1b, xd);
  gemm_mfma<0, float, bf16><<<dim3(256, 6),  256, 0, stream>>>(xd, qkvwt, qkv_b, nullptr, qkv, 1080, 720, 736, 1080, 0);
  attn_kernel<<<3072, 256, 0, stream>>>(qkv, bias_f, xw);
  idwt_kernel<<<12288, 256, 0, stream>>>(xw, xr);
  gemm_mfma<1, float, bf16><<<dim3(1024, 1), 256, 0, stream>>>(xr, pwt, proj_b, x, x1, 180, 192, 192, 180, 180);
  ln_kernel<<<32768, 256, 0, stream>>>(x1, n2w, n2b, yb);
  gemm_mfma<2, float, bf16><<<dim3(1024, 2), 256, 0, stream>>>(yb, f1wt, fc1_b, nullptr, hb, 360, 192, 192, 360, 0);
  gemm_mfma<1, bf16, float><<<dim3(1024, 1), 256, 0, stream>>>(hb, f2wt, fc2_b, x1, out, 180, 360, 384, 180, 180);
}

// Round 4
// 736.593 us; speedup vs baseline: 1.0163x; 1.0163x over previous
//
#include <hip/hip_runtime.h>
#include <hip/hip_bf16.h>
#include <stdint.h>

using bf16 = __hip_bfloat16;
typedef __attribute__((ext_vector_type(8))) short bf16x8;
typedef __attribute__((ext_vector_type(4))) float f32x4;

union U8 { uint4 u; bf16x8 h; };

static __device__ __forceinline__ float b2f(bf16 v) { return __bfloat162float(v); }
static __device__ __forceinline__ bf16  f2b(float v) { return __float2bfloat16(v); }
static __device__ __forceinline__ float toF(float v) { return v; }
static __device__ __forceinline__ float toF(bf16 v)  { return __bfloat162float(v); }
static __device__ __forceinline__ void stF(float* p, float v) { *p = v; }
static __device__ __forceinline__ void stF(bf16* p,  float v) { *p = f2b(v); }
static __device__ __forceinline__ float bfu(unsigned short x) {
  union { unsigned int i; float f; } z; z.i = ((unsigned int)x) << 16; return z.f;
}

// direct global -> LDS async copy, 16B per lane; lds dest = wave-uniform base + lane*16
static __device__ __forceinline__ void gload16(const bf16* g, const short* l) {
  __builtin_amdgcn_global_load_lds(
      (const __attribute__((address_space(1))) void*)g,
      (__attribute__((address_space(3))) void*)l, 16, 0, 0);
}

// ---------------- weight convert: w[k][n] fp32 -> wt[n][k] bf16, k zero-padded to Kp ----
__global__ __launch_bounds__(256) void convert_wt_kernel(
    const float* __restrict__ w, bf16* __restrict__ wt, int K, int N, int Kp)
{
  int idx = blockIdx.x * 256 + threadIdx.x;
  if (idx >= N * Kp) return;
  int n = idx / Kp, k = idx % Kp;
  float v = (k < K) ? w[(size_t)k * N + n] : 0.f;
  wt[idx] = f2b(v);
}

// ---------------- bias concat: [q_b | k_b | v_b] -> 1080 floats ------------------------
__global__ __launch_bounds__(256) void concat_bias_kernel(
    const float* __restrict__ qb, const float* __restrict__ kb,
    const float* __restrict__ vb, float* __restrict__ o)
{
  int i = blockIdx.x * 256 + threadIdx.x;
  if (i >= 1080) return;
  o[i] = (i < 180) ? qb[i] : (i < 360) ? kb[i - 180] : vb[i - 360];
}

// ---------------- bias precompute: bias_f[hh][r][kk] = rpb[rpi[r,kk]*6+hh] --------------
__global__ __launch_bounds__(256) void bias_pre_kernel(
    const int* __restrict__ rpi, const float* __restrict__ rpb, float* __restrict__ bias_f)
{
  int e = blockIdx.x * 256 + threadIdx.x;
  if (e >= 6 * 64 * 144) return;
  int hh = e / 9216, rk = e % 9216;
  bias_f[e] = rpb[rpi[rk] * 6 + hh];
}

// ---------------- LN1 + DWT: x fp32 (2,256,256,180) -> xd bf16 (2,128,128,720) ----------
__global__ __launch_bounds__(256) void ln_dwt_kernel(
    const float* __restrict__ x, const float* __restrict__ w, const float* __restrict__ bia,
    bf16* __restrict__ xd)
{
  __shared__ float nrm[4][180];
  int blk = blockIdx.x;
  int j = blk & 127; int i = (blk >> 7) & 127; int b = blk >> 14;
  int wave = threadIdx.x >> 6, lane = threadIdx.x & 63;
  int ty = wave >> 1, tx = wave & 1;
  size_t tok = (size_t)b * 65536 + (size_t)(2 * i + ty) * 256 + (size_t)(2 * j + tx);
  const float* xp = x + tok * 180;
  float v0 = xp[lane];
  float v1 = xp[lane + 64];
  float v2 = (lane < 52) ? xp[lane + 128] : 0.f;
  float s = v0 + v1 + v2, ss = v0 * v0 + v1 * v1 + v2 * v2;
  #pragma unroll
  for (int m = 32; m; m >>= 1) { s += __shfl_xor(s, m); ss += __shfl_xor(ss, m); }
  float mu = s * (1.f / 180.f);
  float rstd = rsqrtf(ss * (1.f / 180.f) - mu * mu + 1e-5f);
  nrm[wave][lane]      = (v0 - mu) * rstd * w[lane]      + bia[lane];
  nrm[wave][lane + 64] = (v1 - mu) * rstd * w[lane + 64] + bia[lane + 64];
  if (lane < 52)
    nrm[wave][lane + 128] = (v2 - mu) * rstd * w[lane + 128] + bia[lane + 128];
  __syncthreads();
  bf16* op = xd + (size_t)blk * 720;
  for (int o = threadIdx.x; o < 720; o += 256) {
    int g = o / 180, c = o % 180;
    float a = nrm[0][c], bb = nrm[1][c], cc = nrm[2][c], dd = nrm[3][c];
    float r = (g == 0) ? (a + bb + cc + dd)
            : (g == 1) ? (-a - bb + cc + dd)
            : (g == 2) ? (-a + bb - cc + dd)
                       : (a - bb - cc + dd);
    op[o] = f2b(r * 0.5f);
  }
}

// ---------------- plain LN: x1 bf16 (131072,180) -> y bf16 stride 192 (zero-padded) -----
__global__ __launch_bounds__(256) void ln_kernel(
    const bf16* __restrict__ x, const float* __restrict__ w, const float* __restrict__ bia,
    bf16* __restrict__ y)
{
  int wave = threadIdx.x >> 6, lane = threadIdx.x & 63;
  size_t tok = (size_t)blockIdx.x * 4 + wave;
  const bf16* xp = x + tok * 180;
  float v0 = b2f(xp[lane]);
  float v1 = b2f(xp[lane + 64]);
  float v2 = (lane < 52) ? b2f(xp[lane + 128]) : 0.f;
  float s = v0 + v1 + v2, ss = v0 * v0 + v1 * v1 + v2 * v2;
  #pragma unroll
  for (int m = 32; m; m >>= 1) { s += __shfl_xor(s, m); ss += __shfl_xor(ss, m); }
  float mu = s * (1.f / 180.f);
  float rstd = rsqrtf(ss * (1.f / 180.f) - mu * mu + 1e-5f);
  bf16* yp = y + tok * 192;
  yp[lane]      = f2b((v0 - mu) * rstd * w[lane]      + bia[lane]);
  yp[lane + 64] = f2b((v1 - mu) * rstd * w[lane + 64] + bia[lane + 64]);
  if (lane < 52)
    yp[lane + 128] = f2b((v2 - mu) * rstd * w[lane + 128] + bia[lane + 128]);
  else
    yp[lane + 128] = f2b(0.f);
}

// ---------------- MFMA GEMM: out = ep(A@Wt^T + bias [, res]) ----------------------------
// Block tile 128 x 192, waves 2x2 (per-wave 64x96, acc[4][6]).
// Double-buffered LDS + global_load_lds: iteration issues next tile's direct-to-LDS loads
// into buf^1, computes buf, then one __syncthreads (implicit vmcnt0 drain = pipeline wait).
// K-tail: A row slop-reads multiply Wt's zero-padded k in [K,Kp) -> contribute 0.
template <int EP, typename TRes, typename TOut>
__global__ __launch_bounds__(256) void gemm_mfma(
    const bf16* __restrict__ A, const bf16* __restrict__ Wt,
    const float* __restrict__ bias, const TRes* __restrict__ res,
    TOut* __restrict__ out, int N, int lda, int Kp, int ldout, int ldres)
{
  __shared__ __align__(16) short Al[2][128 * 32];
  __shared__ __align__(16) short Bl[2][192 * 32];
  int tid = threadIdx.x;
  int wave = tid >> 6, lane = tid & 63;
  int wy = wave >> 1, wx = wave & 1;
  int m0 = blockIdx.x * 128, n0 = blockIdx.y * 192;

  f32x4 acc[4][6] = {};

  int ar0 = tid >> 2;                 // 0..63
  int ac  = (tid & 3) * 8;            // 0,8,16,24
  const bf16* gA0 = A + (size_t)(m0 + ar0) * lda + ac;
  const bf16* gA1 = A + (size_t)(m0 + 64 + ar0) * lda + ac;
  int br0 = n0 + ar0, br1 = n0 + ar0 + 64, br2 = n0 + ar0 + 128;
  br0 = (br0 < N) ? br0 : (N - 1);
  br1 = (br1 < N) ? br1 : (N - 1);
  br2 = (br2 < N) ? br2 : (N - 1);
  const bf16* gB0 = Wt + (size_t)br0 * Kp + ac;
  const bf16* gB1 = Wt + (size_t)br1 * Kp + ac;
  const bf16* gB2 = Wt + (size_t)br2 * Kp + ac;

  int wb = wave * 512;                // wave-uniform LDS base (shorts)
  int fm = lane & 15, quad = lane >> 4;
  const short* afp = &Al[0][(wy * 64 + fm) * 32 + quad * 8];
  const short* bfp = &Bl[0][(wx * 96 + fm) * 32 + quad * 8];

  // prologue: stage tile 0 into buffer 0
  gload16(gA0, &Al[0][wb]);
  gload16(gA1, &Al[0][2048 + wb]);
  gload16(gB0, &Bl[0][wb]);
  gload16(gB1, &Bl[0][2048 + wb]);
  gload16(gB2, &Bl[0][4096 + wb]);
  __syncthreads();                    // vmcnt(0) drain + barrier

  int cur = 0;
  for (int k0 = 0; k0 < Kp; k0 += 32) {
    int kn = k0 + 32;
    if (kn < Kp) {                    // issue next-tile loads into other buffer
      int nb = cur ^ 1;
      gload16(gA0 + kn, &Al[nb][wb]);
      gload16(gA1 + kn, &Al[nb][2048 + wb]);
      gload16(gB0 + kn, &Bl[nb][wb]);
      gload16(gB1 + kn, &Bl[nb][2048 + wb]);
      gload16(gB2 + kn, &Bl[nb][4096 + wb]);
    }

    int aoff = cur * 4096, boff = cur * 6144;
    bf16x8 af0 = *(const bf16x8*)(afp + aoff);
    bf16x8 af1 = *(const bf16x8*)(afp + aoff + 16 * 32);
    bf16x8 af2 = *(const bf16x8*)(afp + aoff + 32 * 32);
    bf16x8 af3 = *(const bf16x8*)(afp + aoff + 48 * 32);
    #pragma unroll
    for (int nt = 0; nt < 6; nt++) {
      bf16x8 bfr = *(const bf16x8*)(bfp + boff + nt * 16 * 32);
      acc[0][nt] = __builtin_amdgcn_mfma_f32_16x16x32_bf16(af0, bfr, acc[0][nt], 0, 0, 0);
      acc[1][nt] = __builtin_amdgcn_mfma_f32_16x16x32_bf16(af1, bfr, acc[1][nt], 0, 0, 0);
      acc[2][nt] = __builtin_amdgcn_mfma_f32_16x16x32_bf16(af2, bfr, acc[2][nt], 0, 0, 0);
      acc[3][nt] = __builtin_amdgcn_mfma_f32_16x16x32_bf16(af3, bfr, acc[3][nt], 0, 0, 0);
    }

    __syncthreads();                  // waits staged loads (vmcnt0) + guards buf reuse
    cur ^= 1;
  }

  #pragma unroll
  for (int nt = 0; nt < 6; nt++) {
    int col = n0 + wx * 96 + nt * 16 + fm;
    if (col >= N) continue;
    float bv = bias[col];
    #pragma unroll
    for (int mt = 0; mt < 4; mt++) {
      int row0 = m0 + wy * 64 + mt * 16 + quad * 4;
      #pragma unroll
      for (int r = 0; r < 4; r++) {
        int row = row0 + r;
        float v = acc[mt][nt][r] + bv;
        if constexpr (EP == 1) v += toF(res[(size_t)row * ldres + col]);
        if constexpr (EP == 2) v = 0.5f * v * (1.f + erff(v * 0.70710678118654752f));
        stF(&out[(size_t)row * ldout + col], v);
      }
    }
  }
}

// ---------------- MFMA attention: one block per (window, head) --------------------------
// qkv: bf16 fused (32768 x 1080): q cols 0..179, k 180..359, v 360..1079.
// xw out bf16 stride 720; bias_f: [6][64][144]
__global__ __launch_bounds__(256) void attn_kernel(
    const bf16* __restrict__ qkv, const float* __restrict__ bias_f, bf16* __restrict__ xw)
{
  __shared__ short tokl[160];                       // 144 used; -1 = OOB
  __shared__ __align__(16) short Pl[64 * 168];      // P (bf16 bits), cols 144..159 zeroed
  __shared__ __align__(16) short Vt[128 * 168];     // V^T [dd][kk^swz], rows 120..127 zero
  const float scale = 0.18257418583505536f;  // 30^-0.5
  int blk = blockIdx.x;
  int hh = blk % 6; int wid = blk / 6;
  int wj = wid & 15; int wi = (wid >> 4) & 15; int b = wid >> 8;
  int tid = threadIdx.x;
  int wave = tid >> 6, lane = tid & 63;
  int fm = lane & 15, quad = lane >> 4;
  const unsigned int* qkvu = (const unsigned int*)qkv;   // row stride 540 uints
  int hh15 = hh * 15, hh60 = hh * 60;

  // ---- phase 0: kv-position token table ----
  if (tid < 144) {
    int ky = tid / 12, kx = tid % 12;
    int gy = wi * 8 - 4 + ky, gx = wj * 8 - 4 + kx;
    tokl[tid] = (gy >= 0 && gy < 128 && gx >= 0 && gx < 128)
              ? (short)(b * 16384 + gy * 128 + gx) : (short)-1;
  }
  __syncthreads();

  // ---- phase 1: V staging (vectorized). v row offset = 180 uints ----
  {
    int kg = tid & 15, oct = tid >> 4;              // kk offset / dd-oct
    int colx = (oct & 1) << 4;                      // swizzle: col ^= (dd&8)<<1
    #pragma unroll
    for (int p = 0; p < 10; p++) {
      int kk = p * 16 + kg;
      int t = (kk < 144) ? (int)tokl[kk] : -1;
      U8 vv; vv.u = make_uint4(0, 0, 0, 0);
      if (oct < 15 && t >= 0)
        vv.u = *(const uint4*)(qkvu + (size_t)t * 540 + 180 + hh60 + oct * 4);
      short* wp = &Vt[oct * 8 * 168 + (kk ^ colx)];
      #pragma unroll
      for (int jj = 0; jj < 8; jj++) wp[jj * 168] = vv.h[jj];
    }
  }

  // ---- phase 2: QK MFMA with direct-from-global fragments ----
  f32x4 sacc[9] = {};
  {
    U8 qf;
    int r = wave * 16 + fm;
    int gy = wi * 8 + (r >> 3), gx = wj * 8 + (r & 7);
    const unsigned int* qp = qkvu + (size_t)(b * 16384 + gy * 128 + gx) * 540 + hh15 + quad * 4;
    qf.u.x = qp[0]; qf.u.y = qp[1]; qf.u.z = qp[2]; qf.u.w = qp[3];
    if (quad == 3) qf.u.w = 0;                      // zero pad channels 30,31
    #pragma unroll
    for (int nt = 0; nt < 9; nt++) {
      int t = (int)tokl[nt * 16 + fm];
      U8 kf; kf.u = make_uint4(0, 0, 0, 0);
      if (t >= 0) {
        const unsigned int* kp = qkvu + (size_t)t * 540 + 90 + hh15 + quad * 4;
        kf.u.x = kp[0]; kf.u.y = kp[1]; kf.u.z = kp[2]; kf.u.w = kp[3];
      }
      if (quad == 3) kf.u.w = 0;
      sacc[nt] = __builtin_amdgcn_mfma_f32_16x16x32_bf16(qf.h, kf.h, sacc[nt], 0, 0, 0);
    }
  }

  // ---- phase 3: softmax in registers ----
  float sv[9][4];
  const float* bias_g = bias_f + hh * 9216;
  {
    #pragma unroll
    for (int r = 0; r < 4; r++) {
      int row = wave * 16 + quad * 4 + r;
      #pragma unroll
      for (int nt = 0; nt < 9; nt++)
        sv[nt][r] = sacc[nt][r] * scale + bias_g[row * 144 + nt * 16 + fm];
    }
    float mr[4], sr[4];
    #pragma unroll
    for (int r = 0; r < 4; r++) {
      float m = sv[0][r];
      #pragma unroll
      for (int nt = 1; nt < 9; nt++) m = fmaxf(m, sv[nt][r]);
      #pragma unroll
      for (int sh = 1; sh < 16; sh <<= 1) m = fmaxf(m, __shfl_xor(m, sh));
      mr[r] = m;
    }
    #pragma unroll
    for (int r = 0; r < 4; r++) {
      float s = 0.f;
      #pragma unroll
      for (int nt = 0; nt < 9; nt++) { sv[nt][r] = __expf(sv[nt][r] - mr[r]); s += sv[nt][r]; }
      #pragma unroll
      for (int sh = 1; sh < 16; sh <<= 1) s += __shfl_xor(s, sh);
      sr[r] = 1.f / s;
    }
    #pragma unroll
    for (int r = 0; r < 4; r++)
      #pragma unroll
      for (int nt = 0; nt < 9; nt++) sv[nt][r] *= sr[r];
  }

  // ---- phase 4: write normalized P; zero pad cols 144..159 ----
  #pragma unroll
  for (int r = 0; r < 4; r++) {
    int row = wave * 16 + quad * 4 + r;
    #pragma unroll
    for (int nt = 0; nt < 9; nt++)
      Pl[row * 168 + nt * 16 + fm] = (short)__bfloat16_as_ushort(f2b(sv[nt][r]));
  }
  #pragma unroll
  for (int j2 = 0; j2 < 2; j2++) {
    int idx = lane * 2 + j2;
    int row = wave * 16 + (idx >> 3);
    *(unsigned int*)&Pl[row * 168 + 144 + (idx & 7) * 2] = 0u;
  }
  __syncthreads();   // V staging complete (P rows are wave-local)

  // ---- phase 5: O = P @ Vt^T  (M=64, N=128, K=160) ----
  int sread = (fm & 8) << 1;
  bf16x8 pf[5];
  const short* prow = &Pl[(wave * 16 + fm) * 168];
  #pragma unroll
  for (int ks = 0; ks < 5; ks++) pf[ks] = *(const bf16x8*)&prow[ks * 32 + quad * 8];
  f32x4 oacc[8] = {};
  #pragma unroll
  for (int ks = 0; ks < 5; ks++) {
    #pragma unroll
    for (int nt = 0; nt < 8; nt++) {
      bf16x8 vf = *(const bf16x8*)&Vt[(nt * 16 + fm) * 168 + ((ks * 32 + quad * 8) ^ sread)];
      oacc[nt] = __builtin_amdgcn_mfma_f32_16x16x32_bf16(pf[ks], vf, oacc[nt], 0, 0, 0);
    }
  }
  #pragma unroll
  for (int nt = 0; nt < 8; nt++) {
    int col = nt * 16 + fm;
    if (col >= 120) continue;
    #pragma unroll
    for (int r = 0; r < 4; r++) {
      int row = wave * 16 + quad * 4 + r;
      int gy = wi * 8 + (row >> 3), gx = wj * 8 + (row & 7);
      xw[((size_t)b * 16384 + (size_t)gy * 128 + gx) * 720 + hh * 120 + col] = f2b(oacc[nt][r]);
    }
  }
}

// ---------------- IDWT: xw bf16 (.,720) -> xr bf16 stride 192 (zero-padded 180..191) ----
__global__ __launch_bounds__(256) void idwt_kernel(
    const bf16* __restrict__ xw, bf16* __restrict__ xr)
{
  int gid = blockIdx.x * 256 + threadIdx.x;
  int cu = gid % 24;
  int tokn = gid / 24;
  int c = cu * 8;
  bf16* op = xr + (size_t)tokn * 192 + c;
  uint4 outv = make_uint4(0, 0, 0, 0);
  if (c < 184) {
    int x2 = tokn & 255, y2 = (tokn >> 8) & 255, bb = tokn >> 16;
    int ii = y2 >> 1, jj = x2 >> 1, py = y2 & 1, px = x2 & 1;
    const unsigned short* p = (const unsigned short*)xw
        + ((size_t)bb * 16384 + (size_t)ii * 128 + jj) * 720 + c;
    union QW { uint4 v; uint2 u[2]; unsigned short s[8]; } a_, b_, c_, d_, o_;
    a_.u[0] = *(const uint2*)(p);        a_.u[1] = *(const uint2*)(p + 4);
    b_.u[0] = *(const uint2*)(p + 180);  b_.u[1] = *(const uint2*)(p + 184);
    c_.u[0] = *(const uint2*)(p + 360);  c_.u[1] = *(const uint2*)(p + 364);
    d_.u[0] = *(const uint2*)(p + 540);  d_.u[1] = *(const uint2*)(p + 544);
    #pragma unroll
    for (int t = 0; t < 8; t++) {
      float ll = bfu(a_.s[t]), lh = bfu(b_.s[t]), hl = bfu(c_.s[t]), hv = bfu(d_.s[t]);
      float r;
      if (py == 0) r = (px == 0) ? (ll - lh - hl + hv) : (ll - lh + hl - hv);
      else         r = (px == 0) ? (ll + lh - hl - hv) : (ll + lh + hl + hv);
      o_.s[t] = (c + t < 180) ? __bfloat16_as_ushort(f2b(r * 0.5f)) : (unsigned short)0;
    }
    outv = o_.v;
  }
  *(uint4*)op = outv;
}

extern "C" void kernel_launch(void* const* d_in, const int* in_sizes, int n_in,
                              void* d_out, int out_size, void* d_ws, size_t ws_size,
                              hipStream_t stream) {
  (void)in_sizes; (void)n_in; (void)out_size; (void)ws_size;
  const float* x      = (const float*)d_in[0];
  const int*   rpi    = (const int*)  d_in[2];
  const float* n1w    = (const float*)d_in[5];
  const float* n1b    = (const float*)d_in[6];
  const float* q_w    = (const float*)d_in[9];
  const float* q_b    = (const float*)d_in[10];
  const float* k_w    = (const float*)d_in[11];
  const float* k_b    = (const float*)d_in[12];
  const float* v_w    = (const float*)d_in[13];
  const float* v_b    = (const float*)d_in[14];
  const float* rpb    = (const float*)d_in[15];
  const float* proj_w = (const float*)d_in[16];
  const float* proj_b = (const float*)d_in[17];
  const float* n2w    = (const float*)d_in[18];
  const float* n2b    = (const float*)d_in[19];
  const float* fc1_w  = (const float*)d_in[20];
  const float* fc1_b  = (const float*)d_in[21];
  const float* fc2_w  = (const float*)d_in[22];
  const float* fc2_b  = (const float*)d_in[23];
  float* out = (float*)d_out;

  // ---- workspace layout (bf16 elements) ----
  bf16* xd  = (bf16*)d_ws;                  // 32768 x 720   (reused: xw, then yb)
  bf16* qkv = xd + 23592960;                // 32768 x 1080  (q|k|v fused)
  bf16* x1  = qkv + 35389440;               // 131072 x 180
  bf16* hb  = x1 + 23592960;                // 131072 x 360
  bf16* wts = hb + 47185920;
  bf16* qkvwt = wts;                        // 1080 x 736 (q rows 0..179, k 180..359, v 360..1079)
  bf16* pwt  = qkvwt + 794880;              // 180 x 192
  bf16* f1wt = pwt + 34560;                 // 360 x 192
  bf16* f2wt = f1wt + 69120;                // 180 x 384
  float* bias_f = (float*)(f2wt + 69120);   // 6 x 64 x 144 fp32
  float* qkv_b  = bias_f + 55296;           // 1080 fp32
  bf16* xw = xd;
  bf16* xr = qkv + 10223616;                // 131072 x 192 (tail of qkv region)
  bf16* yb = xd;

  convert_wt_kernel<<<518,  256, 0, stream>>>(q_w,    qkvwt,          720, 180, 736);
  convert_wt_kernel<<<518,  256, 0, stream>>>(k_w,    qkvwt + 132480, 720, 180, 736);
  convert_wt_kernel<<<2071, 256, 0, stream>>>(v_w,    qkvwt + 264960, 720, 720, 736);
  convert_wt_kernel<<<135,  256, 0, stream>>>(proj_w, pwt,  180, 180, 192);
  convert_wt_kernel<<<270,  256, 0, stream>>>(fc1_w,  f1wt, 180, 360, 192);
  convert_wt_kernel<<<270,  256, 0, stream>>>(fc2_w,  f2wt, 360, 180, 384);
  concat_bias_kernel<<<5, 256, 0, stream>>>(q_b, k_b, v_b, qkv_b);
  bias_pre_kernel<<<216, 256, 0, stream>>>(rpi, rpb, bias_f);

  ln_dwt_kernel<<<32768, 256, 0, stream>>>(x, n1w, n1b, xd);
  gemm_mfma<0, float, bf16><<<dim3(256, 6),  256, 0, stream>>>(xd, qkvwt, qkv_b, nullptr, qkv, 1080, 720, 736, 1080, 0);
  attn_kernel<<<3072, 256, 0, stream>>>(qkv, bias_f, xw);
  idwt_kernel<<<12288, 256, 0, stream>>>(xw, xr);
  gemm_mfma<1, float, bf16><<<dim3(1024, 1), 256, 0, stream>>>(xr, pwt, proj_b, x, x1, 180, 192, 192, 180, 180);
  ln_kernel<<<32768, 256, 0, stream>>>(x1, n2w, n2b, yb);
  gemm_mfma<2, float, bf16><<<dim3(1024, 2), 256, 0, stream>>>(yb, f1wt, fc1_b, nullptr, hb, 360, 192, 192, 360, 0);
  gemm_mfma<1, bf16, float><<<dim3(1024, 1), 256, 0, stream>>>(hb, f2wt, fc2_b, x1, out, 180, 360, 384, 180, 180);
}

// Round 5
// 727.598 us; speedup vs baseline: 1.0289x; 1.0124x over previous
//
#include <hip/hip_runtime.h>
#include <hip/hip_bf16.h>
#include <stdint.h>

using bf16 = __hip_bfloat16;
typedef __attribute__((ext_vector_type(8))) short bf16x8;
typedef __attribute__((ext_vector_type(4))) float f32x4;

union U8 { uint4 u; bf16x8 h; };

static __device__ __forceinline__ float b2f(bf16 v) { return __bfloat162float(v); }
static __device__ __forceinline__ bf16  f2b(float v) { return __float2bfloat16(v); }
static __device__ __forceinline__ float toF(float v) { return v; }
static __device__ __forceinline__ float toF(bf16 v)  { return __bfloat162float(v); }
static __device__ __forceinline__ void stF(float* p, float v) { *p = v; }
static __device__ __forceinline__ void stF(bf16* p,  float v) { *p = f2b(v); }
static __device__ __forceinline__ float bfu(unsigned short x) {
  union { unsigned int i; float f; } z; z.i = ((unsigned int)x) << 16; return z.f;
}

// direct global -> LDS async copy, 16B per lane; lds dest = wave-uniform base + lane*16
static __device__ __forceinline__ void gload16(const bf16* g, const short* l) {
  __builtin_amdgcn_global_load_lds(
      (const __attribute__((address_space(1))) void*)g,
      (__attribute__((address_space(3))) void*)l, 16, 0, 0);
}

// ---------------- weight convert: w[k][n] fp32 -> wt[n][k] bf16, k zero-padded to Kp ----
__global__ __launch_bounds__(256) void convert_wt_kernel(
    const float* __restrict__ w, bf16* __restrict__ wt, int K, int N, int Kp)
{
  int idx = blockIdx.x * 256 + threadIdx.x;
  if (idx >= N * Kp) return;
  int n = idx / Kp, k = idx % Kp;
  float v = (k < K) ? w[(size_t)k * N + n] : 0.f;
  wt[idx] = f2b(v);
}

// ---------------- bias concat: [q_b | k_b | v_b] -> 1080 floats ------------------------
__global__ __launch_bounds__(256) void concat_bias_kernel(
    const float* __restrict__ qb, const float* __restrict__ kb,
    const float* __restrict__ vb, float* __restrict__ o)
{
  int i = blockIdx.x * 256 + threadIdx.x;
  if (i >= 1080) return;
  o[i] = (i < 180) ? qb[i] : (i < 360) ? kb[i - 180] : vb[i - 360];
}

// ---------------- bias precompute: bias_f[hh][r][kk] = rpb[rpi[r,kk]*6+hh] --------------
__global__ __launch_bounds__(256) void bias_pre_kernel(
    const int* __restrict__ rpi, const float* __restrict__ rpb, float* __restrict__ bias_f)
{
  int e = blockIdx.x * 256 + threadIdx.x;
  if (e >= 6 * 64 * 144) return;
  int hh = e / 9216, rk = e % 9216;
  bias_f[e] = rpb[rpi[rk] * 6 + hh];
}

// ---------------- LN1 + DWT: x fp32 (2,256,256,180) -> xd bf16 (2,128,128,720) ----------
__global__ __launch_bounds__(256) void ln_dwt_kernel(
    const float* __restrict__ x, const float* __restrict__ w, const float* __restrict__ bia,
    bf16* __restrict__ xd)
{
  __shared__ float nrm[4][180];
  int blk = blockIdx.x;
  int j = blk & 127; int i = (blk >> 7) & 127; int b = blk >> 14;
  int wave = threadIdx.x >> 6, lane = threadIdx.x & 63;
  int ty = wave >> 1, tx = wave & 1;
  size_t tok = (size_t)b * 65536 + (size_t)(2 * i + ty) * 256 + (size_t)(2 * j + tx);
  const float* xp = x + tok * 180;
  float v0 = xp[lane];
  float v1 = xp[lane + 64];
  float v2 = (lane < 52) ? xp[lane + 128] : 0.f;
  float s = v0 + v1 + v2, ss = v0 * v0 + v1 * v1 + v2 * v2;
  #pragma unroll
  for (int m = 32; m; m >>= 1) { s += __shfl_xor(s, m); ss += __shfl_xor(ss, m); }
  float mu = s * (1.f / 180.f);
  float rstd = rsqrtf(ss * (1.f / 180.f) - mu * mu + 1e-5f);
  nrm[wave][lane]      = (v0 - mu) * rstd * w[lane]      + bia[lane];
  nrm[wave][lane + 64] = (v1 - mu) * rstd * w[lane + 64] + bia[lane + 64];
  if (lane < 52)
    nrm[wave][lane + 128] = (v2 - mu) * rstd * w[lane + 128] + bia[lane + 128];
  __syncthreads();
  bf16* op = xd + (size_t)blk * 720;
  for (int o = threadIdx.x; o < 720; o += 256) {
    int g = o / 180, c = o % 180;
    float a = nrm[0][c], bb = nrm[1][c], cc = nrm[2][c], dd = nrm[3][c];
    float r = (g == 0) ? (a + bb + cc + dd)
            : (g == 1) ? (-a - bb + cc + dd)
            : (g == 2) ? (-a + bb - cc + dd)
                       : (a - bb - cc + dd);
    op[o] = f2b(r * 0.5f);
  }
}

// ---------------- plain LN: x1 bf16 (131072,180) -> y bf16 stride 192 (zero-padded) -----
__global__ __launch_bounds__(256) void ln_kernel(
    const bf16* __restrict__ x, const float* __restrict__ w, const float* __restrict__ bia,
    bf16* __restrict__ y)
{
  int wave = threadIdx.x >> 6, lane = threadIdx.x & 63;
  size_t tok = (size_t)blockIdx.x * 4 + wave;
  const bf16* xp = x + tok * 180;
  float v0 = b2f(xp[lane]);
  float v1 = b2f(xp[lane + 64]);
  float v2 = (lane < 52) ? b2f(xp[lane + 128]) : 0.f;
  float s = v0 + v1 + v2, ss = v0 * v0 + v1 * v1 + v2 * v2;
  #pragma unroll
  for (int m = 32; m; m >>= 1) { s += __shfl_xor(s, m); ss += __shfl_xor(ss, m); }
  float mu = s * (1.f / 180.f);
  float rstd = rsqrtf(ss * (1.f / 180.f) - mu * mu + 1e-5f);
  bf16* yp = y + tok * 192;
  yp[lane]      = f2b((v0 - mu) * rstd * w[lane]      + bia[lane]);
  yp[lane + 64] = f2b((v1 - mu) * rstd * w[lane + 64] + bia[lane + 64]);
  if (lane < 52)
    yp[lane + 128] = f2b((v2 - mu) * rstd * w[lane + 128] + bia[lane + 128]);
  else
    yp[lane + 128] = f2b(0.f);
}

// ---------------- MFMA GEMM: out = ep(A@Wt^T + bias [, res]) ----------------------------
// Block tile 128 x 192, waves 2x2 (per-wave 64x96, acc[4][6]).
// Counted-vmcnt deep pipeline (T3+T4): 4-buffer ring, depth-3 prefetch via
// global_load_lds; steady-state wait vmcnt(10) (= 5 loads/tile x 2 tiles allowed in
// flight), raw s_barrier + sched_barrier(0). Never drains to 0 in the main loop.
// T2 bank-conflict fix: global SOURCE k-offset XOR-swizzled (q ^= (row>>1)&3), LDS dest
// linear (global_load_lds requirement), fragment reads apply the same involution
// (loop-invariant, folded into afp/bfp).
// Buffer-reuse safety: stage(t+3) overwrites buf[(t-1)&3]; every wave passed barrier_t
// only after finishing compute(t-1) (program order), so no reader remains.
// K-tail: A row slop-reads multiply Wt's zero-padded k in [K,Kp) -> contribute 0.
template <int EP, typename TRes, typename TOut>
__global__ __launch_bounds__(256) void gemm_mfma(
    const bf16* __restrict__ A, const bf16* __restrict__ Wt,
    const float* __restrict__ bias, const TRes* __restrict__ res,
    TOut* __restrict__ out, int N, int lda, int Kp, int ldout, int ldres)
{
  __shared__ __align__(16) short Al[4][128 * 32];   // 32 KB
  __shared__ __align__(16) short Bl[4][192 * 32];   // 48 KB
  int tid = threadIdx.x;
  int wave = tid >> 6, lane = tid & 63;
  int wy = wave >> 1, wx = wave & 1;
  int m0 = blockIdx.x * 128, n0 = blockIdx.y * 192;

  f32x4 acc[4][6] = {};

  int ar0 = tid >> 2;                                  // 0..63 (LDS row within group)
  int acs = ((tid & 3) ^ ((tid >> 3) & 3)) * 8;        // swizzled source k-offset
  const bf16* gA0 = A + (size_t)(m0 + ar0) * lda + acs;
  const bf16* gA1 = A + (size_t)(m0 + 64 + ar0) * lda + acs;
  int br0 = n0 + ar0, br1 = n0 + ar0 + 64, br2 = n0 + ar0 + 128;
  br0 = (br0 < N) ? br0 : (N - 1);
  br1 = (br1 < N) ? br1 : (N - 1);
  br2 = (br2 < N) ? br2 : (N - 1);
  const bf16* gB0 = Wt + (size_t)br0 * Kp + acs;
  const bf16* gB1 = Wt + (size_t)br1 * Kp + acs;
  const bf16* gB2 = Wt + (size_t)br2 * Kp + acs;

  int wb = wave * 512;                // wave-uniform LDS base (shorts)
  int fm = lane & 15, quad = lane >> 4;
  int qsw = (quad ^ ((fm >> 1) & 3)) * 8;              // read-side swizzle (involution)
  const short* afp = &Al[0][(wy * 64 + fm) * 32 + qsw];
  const short* bfp = &Bl[0][(wx * 96 + fm) * 32 + qsw];

  int nt = Kp >> 5;                   // 32-wide K tiles; nt >= 6 for all our shapes

  auto stage = [&](int t) {
    int buf = t & 3, k0 = t * 32;
    gload16(gA0 + k0, &Al[buf][wb]);
    gload16(gA1 + k0, &Al[buf][2048 + wb]);
    gload16(gB0 + k0, &Bl[buf][wb]);
    gload16(gB1 + k0, &Bl[buf][2048 + wb]);
    gload16(gB2 + k0, &Bl[buf][4096 + wb]);
  };
  auto frag_load = [&](int t, bf16x8 (&af)[4], bf16x8 (&bfr)[6]) {
    int aoff = (t & 3) * 4096, boff = (t & 3) * 6144;
    #pragma unroll
    for (int i = 0; i < 4; i++) af[i] = *(const bf16x8*)(afp + aoff + i * 512);
    #pragma unroll
    for (int j = 0; j < 6; j++) bfr[j] = *(const bf16x8*)(bfp + boff + j * 512);
  };
  auto mfma_all = [&](bf16x8 (&af)[4], bf16x8 (&bfr)[6]) {
    __builtin_amdgcn_s_setprio(1);
    #pragma unroll
    for (int i = 0; i < 4; i++)
      #pragma unroll
      for (int j = 0; j < 6; j++)
        acc[i][j] = __builtin_amdgcn_mfma_f32_16x16x32_bf16(af[i], bfr[j], acc[i][j], 0, 0, 0);
    __builtin_amdgcn_s_setprio(0);
  };

  // prologue: depth-3 prefetch
  stage(0); stage(1); stage(2);

  for (int t = 0; t < nt - 3; t++) {
    asm volatile("s_waitcnt vmcnt(10)" ::: "memory");  // tile t landed (own-wave); barrier
    __builtin_amdgcn_s_barrier();                      // extends to all waves' tile-t loads
    __builtin_amdgcn_sched_barrier(0);
    bf16x8 af[4], bfr[6];
    frag_load(t, af, bfr);            // ds_reads BEFORE stage (m201 phase order)
    stage(t + 3);
    mfma_all(af, bfr);
  }
  {
    asm volatile("s_waitcnt vmcnt(10)" ::: "memory");
    __builtin_amdgcn_s_barrier();
    __builtin_amdgcn_sched_barrier(0);
    bf16x8 af[4], bfr[6];
    frag_load(nt - 3, af, bfr);
    mfma_all(af, bfr);
  }
  {
    asm volatile("s_waitcnt vmcnt(5)" ::: "memory");
    __builtin_amdgcn_s_barrier();
    __builtin_amdgcn_sched_barrier(0);
    bf16x8 af[4], bfr[6];
    frag_load(nt - 2, af, bfr);
    mfma_all(af, bfr);
  }
  {
    asm volatile("s_waitcnt vmcnt(0)" ::: "memory");
    __builtin_amdgcn_s_barrier();
    __builtin_amdgcn_sched_barrier(0);
    bf16x8 af[4], bfr[6];
    frag_load(nt - 1, af, bfr);
    mfma_all(af, bfr);
  }

  #pragma unroll
  for (int nt2 = 0; nt2 < 6; nt2++) {
    int col = n0 + wx * 96 + nt2 * 16 + fm;
    if (col >= N) continue;
    float bv = bias[col];
    #pragma unroll
    for (int mt = 0; mt < 4; mt++) {
      int row0 = m0 + wy * 64 + mt * 16 + quad * 4;
      #pragma unroll
      for (int r = 0; r < 4; r++) {
        int row = row0 + r;
        float v = acc[mt][nt2][r] + bv;
        if constexpr (EP == 1) v += toF(res[(size_t)row * ldres + col]);
        if constexpr (EP == 2) v = 0.5f * v * (1.f + erff(v * 0.70710678118654752f));
        stF(&out[(size_t)row * ldout + col], v);
      }
    }
  }
}

// ---------------- MFMA attention: one block per (window, head) --------------------------
// qkv: bf16 fused (32768 x 1080): q cols 0..179, k 180..359, v 360..1079.
// xw out bf16 stride 720; bias_f: [6][64][144]
__global__ __launch_bounds__(256) void attn_kernel(
    const bf16* __restrict__ qkv, const float* __restrict__ bias_f, bf16* __restrict__ xw)
{
  __shared__ short tokl[160];                       // 144 used; -1 = OOB
  __shared__ __align__(16) short Pl[64 * 168];      // P (bf16 bits), cols 144..159 zeroed
  __shared__ __align__(16) short Vt[128 * 168];     // V^T [dd][kk^swz], rows 120..127 zero
  const float scale = 0.18257418583505536f;  // 30^-0.5
  int blk = blockIdx.x;
  int hh = blk % 6; int wid = blk / 6;
  int wj = wid & 15; int wi = (wid >> 4) & 15; int b = wid >> 8;
  int tid = threadIdx.x;
  int wave = tid >> 6, lane = tid & 63;
  int fm = lane & 15, quad = lane >> 4;
  const unsigned int* qkvu = (const unsigned int*)qkv;   // row stride 540 uints
  int hh15 = hh * 15, hh60 = hh * 60;

  // ---- phase 0: kv-position token table ----
  if (tid < 144) {
    int ky = tid / 12, kx = tid % 12;
    int gy = wi * 8 - 4 + ky, gx = wj * 8 - 4 + kx;
    tokl[tid] = (gy >= 0 && gy < 128 && gx >= 0 && gx < 128)
              ? (short)(b * 16384 + gy * 128 + gx) : (short)-1;
  }
  __syncthreads();

  // ---- phase 1: V staging (vectorized). v row offset = 180 uints ----
  {
    int kg = tid & 15, oct = tid >> 4;              // kk offset / dd-oct
    int colx = (oct & 1) << 4;                      // swizzle: col ^= (dd&8)<<1
    #pragma unroll
    for (int p = 0; p < 10; p++) {
      int kk = p * 16 + kg;
      int t = (kk < 144) ? (int)tokl[kk] : -1;
      U8 vv; vv.u = make_uint4(0, 0, 0, 0);
      if (oct < 15 && t >= 0)
        vv.u = *(const uint4*)(qkvu + (size_t)t * 540 + 180 + hh60 + oct * 4);
      short* wp = &Vt[oct * 8 * 168 + (kk ^ colx)];
      #pragma unroll
      for (int jj = 0; jj < 8; jj++) wp[jj * 168] = vv.h[jj];
    }
  }

  // ---- phase 2: QK MFMA with direct-from-global fragments ----
  f32x4 sacc[9] = {};
  {
    U8 qf;
    int r = wave * 16 + fm;
    int gy = wi * 8 + (r >> 3), gx = wj * 8 + (r & 7);
    const unsigned int* qp = qkvu + (size_t)(b * 16384 + gy * 128 + gx) * 540 + hh15 + quad * 4;
    qf.u.x = qp[0]; qf.u.y = qp[1]; qf.u.z = qp[2]; qf.u.w = qp[3];
    if (quad == 3) qf.u.w = 0;                      // zero pad channels 30,31
    #pragma unroll
    for (int nt = 0; nt < 9; nt++) {
      int t = (int)tokl[nt * 16 + fm];
      U8 kf; kf.u = make_uint4(0, 0, 0, 0);
      if (t >= 0) {
        const unsigned int* kp = qkvu + (size_t)t * 540 + 90 + hh15 + quad * 4;
        kf.u.x = kp[0]; kf.u.y = kp[1]; kf.u.z = kp[2]; kf.u.w = kp[3];
      }
      if (quad == 3) kf.u.w = 0;
      sacc[nt] = __builtin_amdgcn_mfma_f32_16x16x32_bf16(qf.h, kf.h, sacc[nt], 0, 0, 0);
    }
  }

  // ---- phase 3: softmax in registers ----
  float sv[9][4];
  const float* bias_g = bias_f + hh * 9216;
  {
    #pragma unroll
    for (int r = 0; r < 4; r++) {
      int row = wave * 16 + quad * 4 + r;
      #pragma unroll
      for (int nt = 0; nt < 9; nt++)
        sv[nt][r] = sacc[nt][r] * scale + bias_g[row * 144 + nt * 16 + fm];
    }
    float mr[4], sr[4];
    #pragma unroll
    for (int r = 0; r < 4; r++) {
      float m = sv[0][r];
      #pragma unroll
      for (int nt = 1; nt < 9; nt++) m = fmaxf(m, sv[nt][r]);
      #pragma unroll
      for (int sh = 1; sh < 16; sh <<= 1) m = fmaxf(m, __shfl_xor(m, sh));
      mr[r] = m;
    }
    #pragma unroll
    for (int r = 0; r < 4; r++) {
      float s = 0.f;
      #pragma unroll
      for (int nt = 0; nt < 9; nt++) { sv[nt][r] = __expf(sv[nt][r] - mr[r]); s += sv[nt][r]; }
      #pragma unroll
      for (int sh = 1; sh < 16; sh <<= 1) s += __shfl_xor(s, sh);
      sr[r] = 1.f / s;
    }
    #pragma unroll
    for (int r = 0; r < 4; r++)
      #pragma unroll
      for (int nt = 0; nt < 9; nt++) sv[nt][r] *= sr[r];
  }

  // ---- phase 4: write normalized P; zero pad cols 144..159 ----
  #pragma unroll
  for (int r = 0; r < 4; r++) {
    int row = wave * 16 + quad * 4 + r;
    #pragma unroll
    for (int nt = 0; nt < 9; nt++)
      Pl[row * 168 + nt * 16 + fm] = (short)__bfloat16_as_ushort(f2b(sv[nt][r]));
  }
  #pragma unroll
  for (int j2 = 0; j2 < 2; j2++) {
    int idx = lane * 2 + j2;
    int row = wave * 16 + (idx >> 3);
    *(unsigned int*)&Pl[row * 168 + 144 + (idx & 7) * 2] = 0u;
  }
  __syncthreads();   // V staging complete (P rows are wave-local)

  // ---- phase 5: O = P @ Vt^T  (M=64, N=128, K=160) ----
  int sread = (fm & 8) << 1;
  bf16x8 pf[5];
  const short* prow = &Pl[(wave * 16 + fm) * 168];
  #pragma unroll
  for (int ks = 0; ks < 5; ks++) pf[ks] = *(const bf16x8*)&prow[ks * 32 + quad * 8];
  f32x4 oacc[8] = {};
  #pragma unroll
  for (int ks = 0; ks < 5; ks++) {
    #pragma unroll
    for (int nt = 0; nt < 8; nt++) {
      bf16x8 vf = *(const bf16x8*)&Vt[(nt * 16 + fm) * 168 + ((ks * 32 + quad * 8) ^ sread)];
      oacc[nt] = __builtin_amdgcn_mfma_f32_16x16x32_bf16(pf[ks], vf, oacc[nt], 0, 0, 0);
    }
  }
  #pragma unroll
  for (int nt = 0; nt < 8; nt++) {
    int col = nt * 16 + fm;
    if (col >= 120) continue;
    #pragma unroll
    for (int r = 0; r < 4; r++) {
      int row = wave * 16 + quad * 4 + r;
      int gy = wi * 8 + (row >> 3), gx = wj * 8 + (row & 7);
      xw[((size_t)b * 16384 + (size_t)gy * 128 + gx) * 720 + hh * 120 + col] = f2b(oacc[nt][r]);
    }
  }
}

// ---------------- IDWT: xw bf16 (.,720) -> xr bf16 stride 192 (zero-padded 180..191) ----
__global__ __launch_bounds__(256) void idwt_kernel(
    const bf16* __restrict__ xw, bf16* __restrict__ xr)
{
  int gid = blockIdx.x * 256 + threadIdx.x;
  int cu = gid % 24;
  int tokn = gid / 24;
  int c = cu * 8;
  bf16* op = xr + (size_t)tokn * 192 + c;
  uint4 outv = make_uint4(0, 0, 0, 0);
  if (c < 184) {
    int x2 = tokn & 255, y2 = (tokn >> 8) & 255, bb = tokn >> 16;
    int ii = y2 >> 1, jj = x2 >> 1, py = y2 & 1, px = x2 & 1;
    const unsigned short* p = (const unsigned short*)xw
        + ((size_t)bb * 16384 + (size_t)ii * 128 + jj) * 720 + c;
    union QW { uint4 v; uint2 u[2]; unsigned short s[8]; } a_, b_, c_, d_, o_;
    a_.u[0] = *(const uint2*)(p);        a_.u[1] = *(const uint2*)(p + 4);
    b_.u[0] = *(const uint2*)(p + 180);  b_.u[1] = *(const uint2*)(p + 184);
    c_.u[0] = *(const uint2*)(p + 360);  c_.u[1] = *(const uint2*)(p + 364);
    d_.u[0] = *(const uint2*)(p + 540);  d_.u[1] = *(const uint2*)(p + 544);
    #pragma unroll
    for (int t = 0; t < 8; t++) {
      float ll = bfu(a_.s[t]), lh = bfu(b_.s[t]), hl = bfu(c_.s[t]), hv = bfu(d_.s[t]);
      float r;
      if (py == 0) r = (px == 0) ? (ll - lh - hl + hv) : (ll - lh + hl - hv);
      else         r = (px == 0) ? (ll + lh - hl - hv) : (ll + lh + hl + hv);
      o_.s[t] = (c + t < 180) ? __bfloat16_as_ushort(f2b(r * 0.5f)) : (unsigned short)0;
    }
    outv = o_.v;
  }
  *(uint4*)op = outv;
}

extern "C" void kernel_launch(void* const* d_in, const int* in_sizes, int n_in,
                              void* d_out, int out_size, void* d_ws, size_t ws_size,
                              hipStream_t stream) {
  (void)in_sizes; (void)n_in; (void)out_size; (void)ws_size;
  const float* x      = (const float*)d_in[0];
  const int*   rpi    = (const int*)  d_in[2];
  const float* n1w    = (const float*)d_in[5];
  const float* n1b    = (const float*)d_in[6];
  const float* q_w    = (const float*)d_in[9];
  const float* q_b    = (const float*)d_in[10];
  const float* k_w    = (const float*)d_in[11];
  const float* k_b    = (const float*)d_in[12];
  const float* v_w    = (const float*)d_in[13];
  const float* v_b    = (const float*)d_in[14];
  const float* rpb    = (const float*)d_in[15];
  const float* proj_w = (const float*)d_in[16];
  const float* proj_b = (const float*)d_in[17];
  const float* n2w    = (const float*)d_in[18];
  const float* n2b    = (const float*)d_in[19];
  const float* fc1_w  = (const float*)d_in[20];
  const float* fc1_b  = (const float*)d_in[21];
  const float* fc2_w  = (const float*)d_in[22];
  const float* fc2_b  = (const float*)d_in[23];
  float* out = (float*)d_out;

  // ---- workspace layout (bf16 elements) ----
  bf16* xd  = (bf16*)d_ws;                  // 32768 x 720   (reused: xw, then yb)
  bf16* qkv = xd + 23592960;                // 32768 x 1080  (q|k|v fused)
  bf16* x1  = qkv + 35389440;               // 131072 x 180
  bf16* hb  = x1 + 23592960;                // 131072 x 360
  bf16* wts = hb + 47185920;
  bf16* qkvwt = wts;                        // 1080 x 736 (q rows 0..179, k 180..359, v 360..1079)
  bf16* pwt  = qkvwt + 794880;              // 180 x 192
  bf16* f1wt = pwt + 34560;                 // 360 x 192
  bf16* f2wt = f1wt + 69120;                // 180 x 384
  float* bias_f = (float*)(f2wt + 69120);   // 6 x 64 x 144 fp32
  float* qkv_b  = bias_f + 55296;           // 1080 fp32
  bf16* xw = xd;
  bf16* xr = qkv + 10223616;                // 131072 x 192 (tail of qkv region)
  bf16* yb = xd;

  convert_wt_kernel<<<518,  256, 0, stream>>>(q_w,    qkvwt,          720, 180, 736);
  convert_wt_kernel<<<518,  256, 0, stream>>>(k_w,    qkvwt + 132480, 720, 180, 736);
  convert_wt_kernel<<<2071, 256, 0, stream>>>(v_w,    qkvwt + 264960, 720, 720, 736);
  convert_wt_kernel<<<135,  256, 0, stream>>>(proj_w, pwt,  180, 180, 192);
  convert_wt_kernel<<<270,  256, 0, stream>>>(fc1_w,  f1wt, 180, 360, 192);
  convert_wt_kernel<<<270,  256, 0, stream>>>(fc2_w,  f2wt, 360, 180, 384);
  concat_bias_kernel<<<5, 256, 0, stream>>>(q_b, k_b, v_b, qkv_b);
  bias_pre_kernel<<<216, 256, 0, stream>>>(rpi, rpb, bias_f);

  ln_dwt_kernel<<<32768, 256, 0, stream>>>(x, n1w, n1b, xd);
  gemm_mfma<0, float, bf16><<<dim3(256, 6),  256, 0, stream>>>(xd, qkvwt, qkv_b, nullptr, qkv, 1080, 720, 736, 1080, 0);
  attn_kernel<<<3072, 256, 0, stream>>>(qkv, bias_f, xw);
  idwt_kernel<<<12288, 256, 0, stream>>>(xw, xr);
  gemm_mfma<1, float, bf16><<<dim3(1024, 1), 256, 0, stream>>>(xr, pwt, proj_b, x, x1, 180, 192, 192, 180, 180);
  ln_kernel<<<32768, 256, 0, stream>>>(x1, n2w, n2b, yb);
  gemm_mfma<2, float, bf16><<<dim3(1024, 2), 256, 0, stream>>>(yb, f1wt, fc1_b, nullptr, hb, 360, 192, 192, 360, 0);
  gemm_mfma<1, bf16, float><<<dim3(1024, 1), 256, 0, stream>>>(hb, f2wt, fc2_b, x1, out, 180, 360, 384, 180, 180);
}